// Round 7
// baseline (65.960 us; speedup 1.0000x reference)
//
#include <hip/hip_runtime.h>

#define B_ 2048
#define S_ 512
#define V_ 32128
#define H_ 16
#define O_ 16

#define NB_ 512                    // total blocks (4 rows each)
#define TB_ 126                    // producer blocks: ceil(V_/256)
#define MAGIC_(i) (0x5EED0C0Du ^ (unsigned)(i))

__device__ __forceinline__ unsigned bf16rne(float f) {
    unsigned x = __float_as_uint(f);
    return (x + 0x7fffu + ((x >> 16) & 1u)) >> 16;
}

// ---------------------------------------------------------------------------
// Fused single-dispatch kernel, NO grid barrier, fixed sync (vs r6):
//   - wT written with PLAIN vectorized stores (cached), then ONE
//     __threadfence() per producer block (buffer_wbl2: L2 -> shared L3)
//     before a relaxed agent mark store.
//   - consumers poll marks with RELAXED agent loads (read-through, no
//     per-poll invalidate) + s_sleep backoff; ONE __threadfence() only if
//     they actually waited.
// Blocks 0..125 transpose 256 columns each, then encode their 4 rows like
// everyone else. 512 blocks x 4 waves = 2048 waves << capacity: all
// co-resident; producers never wait on consumers -> no deadlock.
// Steady-state replays: marks already MAGIC (deterministic data -> wT
// identical) -> no wait, no fence. Harness re-validates on this path.
// ---------------------------------------------------------------------------
__global__ __launch_bounds__(256) void fused_encoder_kernel(
    const int*   __restrict__ x,        // [B, S]
    const float* __restrict__ w,        // [16, V]
    const float* __restrict__ enc1_b,   // [16]
    const float* __restrict__ mean_w,   // [16,16]
    const float* __restrict__ mean_b,   // [16]
    const float* __restrict__ logvar_w, // [16,16]
    const float* __restrict__ logvar_b, // [16]
    uint4*       __restrict__ wT,       // [V][2] packed bf16
    unsigned*    __restrict__ marks,    // [TB_]
    float*       __restrict__ out)      // mean [B,16] then logvar [B,16]
{
    const int t   = threadIdx.x;
    const int blk = blockIdx.x;

    // ---- Producer role: transpose + bf16 downconvert (blocks 0..125) ----
    if (blk < TB_) {
        const int col = blk * 256 + t;
        if (col < V_) {
            float r[16];
#pragma unroll
            for (int h = 0; h < 16; ++h) r[h] = w[(size_t)h * V_ + col];
            unsigned u[8];
#pragma unroll
            for (int k = 0; k < 8; ++k)
                u[k] = bf16rne(r[2 * k]) | (bf16rne(r[2 * k + 1]) << 16);
            wT[(size_t)col * 2 + 0] = make_uint4(u[0], u[1], u[2], u[3]);
            wT[(size_t)col * 2 + 1] = make_uint4(u[4], u[5], u[6], u[7]);
        }
        __syncthreads();   // drains every wave's stores to (at least) L2
        if (t == 0) {
            __threadfence();  // buffer_wbl2: flush this XCD's L2 to shared L3
            __hip_atomic_store(&marks[blk], MAGIC_(blk), __ATOMIC_RELAXED,
                               __HIP_MEMORY_SCOPE_AGENT);
        }
    }

    // ---- Encoder role (r4 structure: one wave per row, zero LDS) ----
    const int wave = t >> 6;
    const int lane = t & 63;
    const int b    = blk * 4 + wave;

    const int g = lane >> 1;   // token group 0..31
    const int p = lane & 1;    // h-half

    // Prefetch epilogue operands up front (hides tail latency).
    const int    o   = lane & 15;
    const int    sel = (lane >> 4) & 1;
    const float* Wrow = (sel ? logvar_w : mean_w) + o * 16;
    float4 w0 = ((const float4*)Wrow)[0];
    float4 w1 = ((const float4*)Wrow)[1];
    float4 w2 = ((const float4*)Wrow)[2];
    float4 w3 = ((const float4*)Wrow)[3];
    float  bv = (sel ? logvar_b : mean_b)[o];
    float4 eb0 = ((const float4*)enc1_b)[p * 2 + 0];
    float4 eb1 = ((const float4*)enc1_b)[p * 2 + 1];

    // Token loads first: 16 independent, overlap HBM latency with the wait.
    const int* xr = x + (size_t)b * S_;
    int v[16];
#pragma unroll
    for (int j = 0; j < 16; ++j)
        v[j] = __builtin_nontemporal_load(xr + j * 32 + g);

    // Wait for the table: RELAXED read-through polls, no per-poll invalidate.
    {
        bool waited = false;
        const int s0 = lane;                               // 0..63  < TB_
        const int s1 = (lane + 64 < TB_) ? lane + 64 : 0;  // 64..125 or 0
        for (;;) {
            unsigned m0 = __hip_atomic_load(&marks[s0], __ATOMIC_RELAXED,
                                            __HIP_MEMORY_SCOPE_AGENT);
            unsigned m1 = __hip_atomic_load(&marks[s1], __ATOMIC_RELAXED,
                                            __HIP_MEMORY_SCOPE_AGENT);
            bool ok = (m0 == MAGIC_(s0)) && (m1 == MAGIC_(s1));
            if (__all(ok)) break;
            waited = true;
            __builtin_amdgcn_s_sleep(2);
        }
        if (waited) __threadfence();   // one-time invalidate: fetch fresh wT
    }

    // Gather-accumulate bf16 table rows (16 B per token per lane).
    float a[8];
#pragma unroll
    for (int k = 0; k < 8; ++k) a[k] = 0.0f;
#pragma unroll
    for (int j = 0; j < 16; ++j) {
        uint4 wv = wT[(size_t)v[j] * 2 + p];
        a[0] += __uint_as_float(wv.x << 16);
        a[1] += __uint_as_float(wv.x & 0xffff0000u);
        a[2] += __uint_as_float(wv.y << 16);
        a[3] += __uint_as_float(wv.y & 0xffff0000u);
        a[4] += __uint_as_float(wv.z << 16);
        a[5] += __uint_as_float(wv.z & 0xffff0000u);
        a[6] += __uint_as_float(wv.w << 16);
        a[7] += __uint_as_float(wv.w & 0xffff0000u);
    }

    // Butterfly across the 32 groups (bit 0 = p preserved).
#pragma unroll
    for (int m = 2; m <= 32; m <<= 1) {
#pragma unroll
        for (int k = 0; k < 8; ++k) a[k] += __shfl_xor(a[k], m);
    }

    // Bias + relu (all lanes redundantly: a[k] = h[8p+k]).
    const float ebv[8] = {eb0.x, eb0.y, eb0.z, eb0.w,
                          eb1.x, eb1.y, eb1.z, eb1.w};
    float hs[8];
#pragma unroll
    for (int k = 0; k < 8; ++k) hs[k] = fmaxf(a[k] + ebv[k], 0.0f);

    // Cross-half exchange via shfl_xor(1).
    float ho[8];
#pragma unroll
    for (int k = 0; k < 8; ++k) ho[k] = __shfl_xor(hs[k], 1);

    float hv[16];
#pragma unroll
    for (int k = 0; k < 8; ++k) {
        hv[k]     = p ? ho[k] : hs[k];
        hv[8 + k] = p ? hs[k] : ho[k];
    }

    // 16x16 matvecs: lanes 0..15 -> mean, 16..31 -> logvar.
    if (lane < 32) {
        float s = bv;
        s += w0.x * hv[0]  + w0.y * hv[1]  + w0.z * hv[2]  + w0.w * hv[3];
        s += w1.x * hv[4]  + w1.y * hv[5]  + w1.z * hv[6]  + w1.w * hv[7];
        s += w2.x * hv[8]  + w2.y * hv[9]  + w2.z * hv[10] + w2.w * hv[11];
        s += w3.x * hv[12] + w3.y * hv[13] + w3.z * hv[14] + w3.w * hv[15];
        __builtin_nontemporal_store(
            s, out + (size_t)sel * B_ * O_ + (size_t)b * O_ + o);
    }
}

// ---------------------------------------------------------------------------
// Fallback (no workspace): f32 direct gather, block-per-row (proven r1 path).
// ---------------------------------------------------------------------------
__global__ __launch_bounds__(256) void encoder_f32_fallback_kernel(
    const int*   __restrict__ x,
    const float* __restrict__ table,    // [16, V]
    const float* __restrict__ enc1_b,
    const float* __restrict__ mean_w,
    const float* __restrict__ mean_b,
    const float* __restrict__ logvar_w,
    const float* __restrict__ logvar_b,
    float*       __restrict__ out)
{
    __shared__ int   toks[S_];
    __shared__ float hred[4][16];
    __shared__ float hvec[16];

    const int t = threadIdx.x;
    const int b = blockIdx.x;
    {
        const int2* xr = (const int2*)(x + (size_t)b * S_);
        ((int2*)toks)[t] = xr[t];
    }
    __syncthreads();

    const int q = t & 3;
    const int g = t >> 2;
    float a0 = 0.f, a1 = 0.f, a2 = 0.f, a3 = 0.f;
#pragma unroll
    for (int j = 0; j < 8; ++j) {
        int v = toks[j * 64 + g];
        a0 += table[(size_t)(q * 4 + 0) * V_ + v];
        a1 += table[(size_t)(q * 4 + 1) * V_ + v];
        a2 += table[(size_t)(q * 4 + 2) * V_ + v];
        a3 += table[(size_t)(q * 4 + 3) * V_ + v];
    }
#pragma unroll
    for (int m = 4; m <= 32; m <<= 1) {
        a0 += __shfl_xor(a0, m);
        a1 += __shfl_xor(a1, m);
        a2 += __shfl_xor(a2, m);
        a3 += __shfl_xor(a3, m);
    }
    const int wave = t >> 6;
    const int lane = t & 63;
    if (lane < 4) {
        hred[wave][lane * 4 + 0] = a0;
        hred[wave][lane * 4 + 1] = a1;
        hred[wave][lane * 4 + 2] = a2;
        hred[wave][lane * 4 + 3] = a3;
    }
    __syncthreads();
    if (t < 16) {
        float s = hred[0][t] + hred[1][t] + hred[2][t] + hred[3][t] + enc1_b[t];
        hvec[t] = fmaxf(s, 0.0f);
    }
    __syncthreads();
    if (t < 32) {
        const int    o  = t & 15;
        const float* W  = (t < 16) ? mean_w : logvar_w;
        const float* Bv = (t < 16) ? mean_b : logvar_b;
        float s = Bv[o];
#pragma unroll
        for (int k = 0; k < 16; ++k) s += W[o * 16 + k] * hvec[k];
        const size_t off = (t < 16) ? 0 : (size_t)B_ * O_;
        out[off + (size_t)b * O_ + o] = s;
    }
}

extern "C" void kernel_launch(void* const* d_in, const int* in_sizes, int n_in,
                              void* d_out, int out_size, void* d_ws, size_t ws_size,
                              hipStream_t stream) {
    const int*   x        = (const int*)d_in[0];
    const float* enc1_w   = (const float*)d_in[1];
    const float* enc1_b   = (const float*)d_in[2];
    const float* mean_w   = (const float*)d_in[3];
    const float* mean_b   = (const float*)d_in[4];
    const float* logvar_w = (const float*)d_in[5];
    const float* logvar_b = (const float*)d_in[6];
    float*       out      = (float*)d_out;

    const size_t wT_bytes   = (size_t)V_ * H_ * 2;          // ~1 MB
    const size_t need_bytes = wT_bytes + TB_ * sizeof(unsigned);
    if (ws_size >= need_bytes) {
        uint4*    wT    = (uint4*)d_ws;
        unsigned* marks = (unsigned*)((char*)d_ws + wT_bytes);
        fused_encoder_kernel<<<NB_, 256, 0, stream>>>(
            x, enc1_w, enc1_b, mean_w, mean_b, logvar_w, logvar_b,
            wT, marks, out);
    } else {
        encoder_f32_fallback_kernel<<<B_, 256, 0, stream>>>(
            x, enc1_w, enc1_b, mean_w, mean_b, logvar_w, logvar_b, out);
    }
}

// Round 8
// 16.807 us; speedup vs baseline: 3.9245x; 3.9245x over previous
//
#include <hip/hip_runtime.h>

#define B_ 2048
#define S_ 512
#define V_ 32128
#define H_ 16
#define O_ 16

__device__ __forceinline__ unsigned bf16rne(float f) {
    unsigned x = __float_as_uint(f);
    return (x + 0x7fffu + ((x >> 16) & 1u)) >> 16;
}

// ---------------------------------------------------------------------------
// Register transpose + bf16 downconvert: enc1_w [16, V] f32 -> wT [V][8] u32
// (packed bf16 pairs, 32 B per token). 64-thread blocks, 1 column/thread,
// grid 502 -> spread across ~251 CUs. No LDS, no barriers. V = 502*64.
// Plain cached stores: wT stays L2-resident for the encoder's gathers.
// ---------------------------------------------------------------------------
__global__ __launch_bounds__(64) void transpose_w_bf16_kernel(
    const float* __restrict__ w,      // [16, V]
    uint4* __restrict__ wT)           // [V][2] uint4
{
    const int col = blockIdx.x * 64 + threadIdx.x;

    float r[16];
#pragma unroll
    for (int h = 0; h < 16; ++h) r[h] = w[(size_t)h * V_ + col];

    unsigned u[8];
#pragma unroll
    for (int k = 0; k < 8; ++k)
        u[k] = bf16rne(r[2 * k]) | (bf16rne(r[2 * k + 1]) << 16);

    wT[(size_t)col * 2 + 0] = make_uint4(u[0], u[1], u[2], u[3]);
    wT[(size_t)col * 2 + 1] = make_uint4(u[4], u[5], u[6], u[7]);
}

// ---------------------------------------------------------------------------
// One WAVE per batch row, zero LDS, zero barriers (r4 structure - measured
// best: 16.94 us total). lane = 2g + p: group g handles tokens j*32+g;
// half p owns h[8p..8p+8). Tokens read directly from x (coalesced 128B per
// j, nontemporal: don't evict wT from L2). Butterfly reduce over g;
// cross-half exchange via shfl_xor(1); 16x16 matvecs on lanes 0..31 with
// prefetched W rows.
// ---------------------------------------------------------------------------
__global__ __launch_bounds__(256) void encoder_bf16_kernel(
    const int*   __restrict__ x,        // [B, S]
    const uint4* __restrict__ wT,       // [V][2]
    const float* __restrict__ enc1_b,   // [16]
    const float* __restrict__ mean_w,   // [16,16]
    const float* __restrict__ mean_b,   // [16]
    const float* __restrict__ logvar_w, // [16,16]
    const float* __restrict__ logvar_b, // [16]
    float*       __restrict__ out)      // mean [B,16] then logvar [B,16]
{
    const int t    = threadIdx.x;
    const int wave = t >> 6;
    const int lane = t & 63;
    const int b    = blockIdx.x * 4 + wave;

    const int g = lane >> 1;   // token group
    const int p = lane & 1;    // h-half

    // Prefetch epilogue operands up front (hides tail latency).
    const int    o   = lane & 15;
    const int    sel = (lane >> 4) & 1;
    const float* Wrow = (sel ? logvar_w : mean_w) + o * 16;
    float4 w0 = ((const float4*)Wrow)[0];
    float4 w1 = ((const float4*)Wrow)[1];
    float4 w2 = ((const float4*)Wrow)[2];
    float4 w3 = ((const float4*)Wrow)[3];
    float  bv = (sel ? logvar_b : mean_b)[o];
    float4 eb = ((const float4*)enc1_b)[p * 2 + 0];
    float4 eb2 = ((const float4*)enc1_b)[p * 2 + 1];

    // Token loads: 16 independent, nontemporal.
    const int* xr = x + (size_t)b * S_;
    int v[16];
#pragma unroll
    for (int j = 0; j < 16; ++j)
        v[j] = __builtin_nontemporal_load(xr + j * 32 + g);

    // Gather-accumulate bf16 table rows.
    float a[8];
#pragma unroll
    for (int k = 0; k < 8; ++k) a[k] = 0.0f;
#pragma unroll
    for (int j = 0; j < 16; ++j) {
        uint4 wv = wT[(size_t)v[j] * 2 + p];
        a[0] += __uint_as_float(wv.x << 16);
        a[1] += __uint_as_float(wv.x & 0xffff0000u);
        a[2] += __uint_as_float(wv.y << 16);
        a[3] += __uint_as_float(wv.y & 0xffff0000u);
        a[4] += __uint_as_float(wv.z << 16);
        a[5] += __uint_as_float(wv.z & 0xffff0000u);
        a[6] += __uint_as_float(wv.w << 16);
        a[7] += __uint_as_float(wv.w & 0xffff0000u);
    }

    // Butterfly across the 32 groups (bit 0 = p preserved).
#pragma unroll
    for (int m = 2; m <= 32; m <<= 1) {
#pragma unroll
        for (int k = 0; k < 8; ++k) a[k] += __shfl_xor(a[k], m);
    }

    // Bias + relu (all lanes redundantly: a[k] = h[8p+k]).
    const float ebv[8] = {eb.x, eb.y, eb.z, eb.w, eb2.x, eb2.y, eb2.z, eb2.w};
    float hs[8];
#pragma unroll
    for (int k = 0; k < 8; ++k) hs[k] = fmaxf(a[k] + ebv[k], 0.0f);

    // Cross-half exchange: other half's 8 h's via shfl_xor(1).
    float ho[8];
#pragma unroll
    for (int k = 0; k < 8; ++k) ho[k] = __shfl_xor(hs[k], 1);

    float hv[16];
#pragma unroll
    for (int k = 0; k < 8; ++k) {
        hv[k]     = p ? ho[k] : hs[k];   // h[0..8)
        hv[8 + k] = p ? hs[k] : ho[k];   // h[8..16)
    }

    // 16x16 matvecs: lanes 0..15 -> mean, 16..31 -> logvar.
    if (lane < 32) {
        float s = bv;
        s += w0.x * hv[0]  + w0.y * hv[1]  + w0.z * hv[2]  + w0.w * hv[3];
        s += w1.x * hv[4]  + w1.y * hv[5]  + w1.z * hv[6]  + w1.w * hv[7];
        s += w2.x * hv[8]  + w2.y * hv[9]  + w2.z * hv[10] + w2.w * hv[11];
        s += w3.x * hv[12] + w3.y * hv[13] + w3.z * hv[14] + w3.w * hv[15];
        __builtin_nontemporal_store(
            s, out + (size_t)sel * B_ * O_ + (size_t)b * O_ + o);
    }
}

// ---------------------------------------------------------------------------
// Fallback (no workspace): f32 direct gather, block-per-row (proven r1 path).
// ---------------------------------------------------------------------------
__global__ __launch_bounds__(256) void encoder_f32_fallback_kernel(
    const int*   __restrict__ x,
    const float* __restrict__ table,    // [16, V]
    const float* __restrict__ enc1_b,
    const float* __restrict__ mean_w,
    const float* __restrict__ mean_b,
    const float* __restrict__ logvar_w,
    const float* __restrict__ logvar_b,
    float*       __restrict__ out)
{
    __shared__ int   toks[S_];
    __shared__ float hred[4][16];
    __shared__ float hvec[16];

    const int t = threadIdx.x;
    const int b = blockIdx.x;
    {
        const int2* xr = (const int2*)(x + (size_t)b * S_);
        ((int2*)toks)[t] = xr[t];
    }
    __syncthreads();

    const int q = t & 3;
    const int g = t >> 2;
    float a0 = 0.f, a1 = 0.f, a2 = 0.f, a3 = 0.f;
#pragma unroll
    for (int j = 0; j < 8; ++j) {
        int v = toks[j * 64 + g];
        a0 += table[(size_t)(q * 4 + 0) * V_ + v];
        a1 += table[(size_t)(q * 4 + 1) * V_ + v];
        a2 += table[(size_t)(q * 4 + 2) * V_ + v];
        a3 += table[(size_t)(q * 4 + 3) * V_ + v];
    }
#pragma unroll
    for (int m = 4; m <= 32; m <<= 1) {
        a0 += __shfl_xor(a0, m);
        a1 += __shfl_xor(a1, m);
        a2 += __shfl_xor(a2, m);
        a3 += __shfl_xor(a3, m);
    }
    const int wave = t >> 6;
    const int lane = t & 63;
    if (lane < 4) {
        hred[wave][lane * 4 + 0] = a0;
        hred[wave][lane * 4 + 1] = a1;
        hred[wave][lane * 4 + 2] = a2;
        hred[wave][lane * 4 + 3] = a3;
    }
    __syncthreads();
    if (t < 16) {
        float s = hred[0][t] + hred[1][t] + hred[2][t] + hred[3][t] + enc1_b[t];
        hvec[t] = fmaxf(s, 0.0f);
    }
    __syncthreads();
    if (t < 32) {
        const int    o  = t & 15;
        const float* W  = (t < 16) ? mean_w : logvar_w;
        const float* Bv = (t < 16) ? mean_b : logvar_b;
        float s = Bv[o];
#pragma unroll
        for (int k = 0; k < 16; ++k) s += W[o * 16 + k] * hvec[k];
        const size_t off = (t < 16) ? 0 : (size_t)B_ * O_;
        out[off + (size_t)b * O_ + o] = s;
    }
}

extern "C" void kernel_launch(void* const* d_in, const int* in_sizes, int n_in,
                              void* d_out, int out_size, void* d_ws, size_t ws_size,
                              hipStream_t stream) {
    const int*   x        = (const int*)d_in[0];
    const float* enc1_w   = (const float*)d_in[1];
    const float* enc1_b   = (const float*)d_in[2];
    const float* mean_w   = (const float*)d_in[3];
    const float* mean_b   = (const float*)d_in[4];
    const float* logvar_w = (const float*)d_in[5];
    const float* logvar_b = (const float*)d_in[6];
    float*       out      = (float*)d_out;

    const size_t wT_bytes = (size_t)V_ * H_ * 2;   // bf16 table, ~1 MB
    if (ws_size >= wT_bytes) {
        uint4* wT = (uint4*)d_ws;
        transpose_w_bf16_kernel<<<V_ / 64, 64, 0, stream>>>(enc1_w, wT);
        encoder_bf16_kernel<<<B_ / 4, 256, 0, stream>>>(
            x, wT, enc1_b, mean_w, mean_b, logvar_w, logvar_b, out);
    } else {
        encoder_f32_fallback_kernel<<<B_, 256, 0, stream>>>(
            x, enc1_w, enc1_b, mean_w, mean_b, logvar_w, logvar_b, out);
    }
}